// Round 1
// baseline (176.026 us; speedup 1.0000x reference)
//
#include <hip/hip_runtime.h>

#define NROWS 8192
#define NCOLS 4096
#define LAMB  0.1

// ---------------------------------------------------------------------------
// Kernel 1: per-row squared error sum. One 256-thread block per row.
// Row = 4096 f32 = 1024 float4; each thread loads 4 float4 from each input.
// Memory-bound: 256 MiB total read.
// ---------------------------------------------------------------------------
__global__ __launch_bounds__(256) void rowerr_kernel(const float* __restrict__ inp,
                                                     const float* __restrict__ tgt,
                                                     float* __restrict__ err) {
    const int row = blockIdx.x;
    const float4* a = reinterpret_cast<const float4*>(inp + (size_t)row * NCOLS);
    const float4* b = reinterpret_cast<const float4*>(tgt + (size_t)row * NCOLS);
    const int t = threadIdx.x;

    float acc = 0.f;
#pragma unroll
    for (int c = 0; c < 4; ++c) {
        float4 va = a[t + c * 256];
        float4 vb = b[t + c * 256];
        float dx = va.x - vb.x;
        float dy = va.y - vb.y;
        float dz = va.z - vb.z;
        float dw = va.w - vb.w;
        acc += dx * dx + dy * dy + dz * dz + dw * dw;
    }

    // wave (64-lane) reduce
#pragma unroll
    for (int off = 32; off > 0; off >>= 1) acc += __shfl_down(acc, off, 64);

    __shared__ float ws[4];
    const int lane = t & 63, wv = t >> 6;
    if (lane == 0) ws[wv] = acc;
    __syncthreads();
    if (t == 0) err[row] = ws[0] + ws[1] + ws[2] + ws[3];
}

// ---------------------------------------------------------------------------
// Kernel 2: single block, 1024 threads.
//  - load 8192 errs into LDS (32 KB)
//  - bitonic sort ascending in LDS
//  - fused f64 scan of (x, x^2): per-thread 8-elem local sums -> wave shfl
//    scan -> 16 wave totals in LDS -> exclusive per-thread offsets
//  - evaluate obj[k] on the fly, argmin with first-index tie-break,
//    carrying cs[k] (inlier sum) along
//  - thread 0 writes out = cs[i]/(i+1) + LAMB * obj[i]
// ---------------------------------------------------------------------------
__global__ __launch_bounds__(1024) void drae_kernel(const float* __restrict__ err,
                                                    float* __restrict__ out) {
    const int N = NROWS;
    __shared__ float s[NROWS];        // 32 KB
    __shared__ double auxX[16], auxX2[16];
    __shared__ double redObj[16], redCs[16];
    __shared__ int    redIdx[16];

    const int tid = threadIdx.x;

    for (int i = tid; i < N; i += 1024) s[i] = err[i];
    __syncthreads();

    // ---- bitonic sort (ascending), 91 barrier passes ----
    for (int k = 2; k <= N; k <<= 1) {
        for (int j = k >> 1; j > 0; j >>= 1) {
            for (int i = tid; i < N; i += 1024) {
                const int ixj = i ^ j;
                if (ixj > i) {
                    const float a = s[i];
                    const float b = s[ixj];
                    const bool up = ((i & k) == 0);
                    if (up ? (a > b) : (a < b)) { s[i] = b; s[ixj] = a; }
                }
            }
            __syncthreads();
        }
    }

    // ---- per-thread local sums over 8 contiguous sorted elements ----
    float v[8];
    double sx = 0.0, sx2 = 0.0;
#pragma unroll
    for (int r = 0; r < 8; ++r) {
        v[r] = s[tid * 8 + r];
        sx  += (double)v[r];
        sx2 += (double)v[r] * (double)v[r];
    }

    // ---- wave-level inclusive scan of (sx, sx2) ----
    const int lane = tid & 63, wv = tid >> 6;
    double ix = sx, ix2 = sx2;
#pragma unroll
    for (int off = 1; off < 64; off <<= 1) {
        double t1 = __shfl_up(ix, off, 64);
        double t2 = __shfl_up(ix2, off, 64);
        if (lane >= off) { ix += t1; ix2 += t2; }
    }
    if (lane == 63) { auxX[wv] = ix; auxX2[wv] = ix2; }
    __syncthreads();

    double wOff1 = 0.0, wOff2 = 0.0, total1 = 0.0, total2 = 0.0;
#pragma unroll
    for (int w = 0; w < 16; ++w) {
        const double a1 = auxX[w], a2 = auxX2[w];
        if (w < wv) { wOff1 += a1; wOff2 += a2; }
        total1 += a1;
        total2 += a2;
    }
    const double exc1 = wOff1 + (ix - sx);     // exclusive prefix before this chunk
    const double exc2 = wOff2 + (ix2 - sx2);

    const double nf = (double)N;
    const double Sb = total2 - total1 * total1 / nf;

    // ---- on-the-fly objective evaluation + local argmin ----
    double run1 = exc1, run2 = exc2;
    double bestObj = 1e300, bestCs = 0.0;
    int bestIdx = N;
#pragma unroll
    for (int r = 0; r < 8; ++r) {
        const int idx = tid * 8 + r;
        run1 += (double)v[r];
        run2 += (double)v[r] * (double)v[r];
        if (idx < N - 1) {
            const double kf  = (double)(idx + 1);
            const double Sw1 = run2 - run1 * run1 / kf;
            const double rem = total1 - run1;
            const double Sw2 = total2 - run2 - rem * rem / (nf - kf);
            const double obj = (Sw1 + Sw2) / Sb;
            if (obj < bestObj) { bestObj = obj; bestIdx = idx; bestCs = run1; }
        }
    }

    // ---- wave argmin reduce (min obj, first index on ties) ----
#pragma unroll
    for (int off = 32; off > 0; off >>= 1) {
        const double oObj = __shfl_down(bestObj, off, 64);
        const int    oIdx = __shfl_down(bestIdx, off, 64);
        const double oCs  = __shfl_down(bestCs, off, 64);
        if (oObj < bestObj || (oObj == bestObj && oIdx < bestIdx)) {
            bestObj = oObj; bestIdx = oIdx; bestCs = oCs;
        }
    }
    if (lane == 0) { redObj[wv] = bestObj; redIdx[wv] = bestIdx; redCs[wv] = bestCs; }
    __syncthreads();

    if (tid == 0) {
        double bObj = redObj[0], bCs = redCs[0];
        int bIdx = redIdx[0];
        for (int w = 1; w < 16; ++w) {
            if (redObj[w] < bObj || (redObj[w] == bObj && redIdx[w] < bIdx)) {
                bObj = redObj[w]; bIdx = redIdx[w]; bCs = redCs[w];
            }
        }
        const double T = (double)(bIdx + 1);
        out[0] = (float)(bCs / T + LAMB * bObj);
    }
}

// ---------------------------------------------------------------------------
extern "C" void kernel_launch(void* const* d_in, const int* in_sizes, int n_in,
                              void* d_out, int out_size, void* d_ws, size_t ws_size,
                              hipStream_t stream) {
    const float* inp = (const float*)d_in[0];
    const float* tgt = (const float*)d_in[1];
    float* errbuf = (float*)d_ws;   // 8192 f32 = 32 KB scratch

    rowerr_kernel<<<NROWS, 256, 0, stream>>>(inp, tgt, errbuf);
    drae_kernel<<<1, 1024, 0, stream>>>(errbuf, (float*)d_out);
}

// Round 2
// 75.905 us; speedup vs baseline: 2.3191x; 2.3191x over previous
//
#include <hip/hip_runtime.h>

#define NROWS 8192
#define NCOLS 4096
#define LAMB  0.1

// ---------------------------------------------------------------------------
// Kernel 1: per-row squared error sum. One 256-thread block per row.
// Memory-bound: 256 MiB total read -> ~41 us (at HBM roofline).
// ---------------------------------------------------------------------------
__global__ __launch_bounds__(256) void rowerr_kernel(const float* __restrict__ inp,
                                                     const float* __restrict__ tgt,
                                                     float* __restrict__ err) {
    const int row = blockIdx.x;
    const float4* a = reinterpret_cast<const float4*>(inp + (size_t)row * NCOLS);
    const float4* b = reinterpret_cast<const float4*>(tgt + (size_t)row * NCOLS);
    const int t = threadIdx.x;

    float acc = 0.f;
#pragma unroll
    for (int c = 0; c < 4; ++c) {
        float4 va = a[t + c * 256];
        float4 vb = b[t + c * 256];
        float dx = va.x - vb.x;
        float dy = va.y - vb.y;
        float dz = va.z - vb.z;
        float dw = va.w - vb.w;
        acc += dx * dx + dy * dy + dz * dz + dw * dw;
    }

#pragma unroll
    for (int off = 32; off > 0; off >>= 1) acc += __shfl_down(acc, off, 64);

    __shared__ float ws[4];
    const int lane = t & 63, wv = t >> 6;
    if (lane == 0) ws[wv] = acc;
    __syncthreads();
    if (t == 0) err[row] = ws[0] + ws[1] + ws[2] + ws[3];
}

// ---------------------------------------------------------------------------
// Kernel 2: single block, 1024 threads, 8 elements/thread IN REGISTERS.
// Bitonic sort hybrid:
//   j in {1,2,4}   -> intra-thread register compare-exchange (no barrier)
//   j in {8..256}  -> intra-wave __shfl_xor               (no barrier)
//   j in {512..4096} -> LDS round trip                    (2 barriers each, 10 passes)
// Then fused f64 scan of (x, x^2) + on-the-fly objective argmin.
// ---------------------------------------------------------------------------
__global__ __launch_bounds__(1024) void drae_kernel(const float* __restrict__ err,
                                                    float* __restrict__ out) {
    const int N = NROWS;
    __shared__ float s[NROWS];        // 32 KB, used only for cross-wave passes
    __shared__ double auxX[16], auxX2[16];
    __shared__ double redObj[16], redCs[16];
    __shared__ int    redIdx[16];

    const int tid = threadIdx.x;
    const int lane = tid & 63, wv = tid >> 6;

    // load 8 contiguous elements into registers (two float4)
    float v[8];
    {
        const float4* e4 = reinterpret_cast<const float4*>(err);
        float4 a = e4[tid * 2];
        float4 b = e4[tid * 2 + 1];
        v[0] = a.x; v[1] = a.y; v[2] = a.z; v[3] = a.w;
        v[4] = b.x; v[5] = b.y; v[6] = b.z; v[7] = b.w;
    }

#define CEPAIR(ra, rb)                                                \
    {                                                                 \
        const bool up = (((tid << 3) + (ra)) & k) == 0;               \
        const float a_ = v[ra], b_ = v[rb];                           \
        v[ra] = up ? fminf(a_, b_) : fmaxf(a_, b_);                   \
        v[rb] = up ? fmaxf(a_, b_) : fminf(a_, b_);                   \
    }

#pragma unroll
    for (int kk = 1; kk <= 13; ++kk) {
        const int k = 1 << kk;

        // ---- cross-wave passes: j >= 512, via LDS ----
        for (int j = k >> 1; j >= 512; j >>= 1) {
#pragma unroll
            for (int r = 0; r < 8; ++r) s[(tid << 3) + r] = v[r];
            __syncthreads();
#pragma unroll
            for (int r = 0; r < 8; ++r) {
                const int i = (tid << 3) + r;
                const float pv = s[i ^ j];
                const bool amLow = (i & j) == 0;
                const bool up = (i & k) == 0;
                v[r] = (amLow == up) ? fminf(v[r], pv) : fmaxf(v[r], pv);
            }
            __syncthreads();
        }

        // ---- intra-wave passes: 8 <= j <= 256, via shuffle ----
        {
            const int jstart = ((k >> 1) > 256) ? 256 : (k >> 1);
            for (int j = jstart; j >= 8; j >>= 1) {
                const int m = j >> 3;                 // lane xor mask
                const bool amLow = (lane & m) == 0;
                const bool up = ((tid << 3) & k) == 0;   // k >= 16 here
#pragma unroll
                for (int r = 0; r < 8; ++r) {
                    const float pv = __shfl_xor(v[r], m, 64);
                    v[r] = (amLow == up) ? fminf(v[r], pv) : fmaxf(v[r], pv);
                }
            }
        }

        // ---- intra-thread passes: j in {4,2,1} (compile-time indices) ----
        if (k >= 8) {
            CEPAIR(0, 4) CEPAIR(1, 5) CEPAIR(2, 6) CEPAIR(3, 7)   // j=4
            CEPAIR(0, 2) CEPAIR(1, 3) CEPAIR(4, 6) CEPAIR(5, 7)   // j=2
            CEPAIR(0, 1) CEPAIR(2, 3) CEPAIR(4, 5) CEPAIR(6, 7)   // j=1
        } else if (k == 4) {
            CEPAIR(0, 2) CEPAIR(1, 3) CEPAIR(4, 6) CEPAIR(5, 7)   // j=2
            CEPAIR(0, 1) CEPAIR(2, 3) CEPAIR(4, 5) CEPAIR(6, 7)   // j=1
        } else {  // k == 2
            CEPAIR(0, 1) CEPAIR(2, 3) CEPAIR(4, 5) CEPAIR(6, 7)   // j=1
        }
    }
#undef CEPAIR

    // ---- per-thread local sums over the 8 sorted elements (already in regs) ----
    double sx = 0.0, sx2 = 0.0;
#pragma unroll
    for (int r = 0; r < 8; ++r) {
        sx  += (double)v[r];
        sx2 += (double)v[r] * (double)v[r];
    }

    // ---- wave-level inclusive scan of (sx, sx2) ----
    double ix = sx, ix2 = sx2;
#pragma unroll
    for (int off = 1; off < 64; off <<= 1) {
        double t1 = __shfl_up(ix, off, 64);
        double t2 = __shfl_up(ix2, off, 64);
        if (lane >= off) { ix += t1; ix2 += t2; }
    }
    if (lane == 63) { auxX[wv] = ix; auxX2[wv] = ix2; }
    __syncthreads();

    double wOff1 = 0.0, wOff2 = 0.0, total1 = 0.0, total2 = 0.0;
#pragma unroll
    for (int w = 0; w < 16; ++w) {
        const double a1 = auxX[w], a2 = auxX2[w];
        if (w < wv) { wOff1 += a1; wOff2 += a2; }
        total1 += a1;
        total2 += a2;
    }
    const double exc1 = wOff1 + (ix - sx);     // exclusive prefix before this chunk
    const double exc2 = wOff2 + (ix2 - sx2);

    const double nf = (double)N;
    const double Sb = total2 - total1 * total1 / nf;

    // ---- on-the-fly objective evaluation + local argmin ----
    double run1 = exc1, run2 = exc2;
    double bestObj = 1e300, bestCs = 0.0;
    int bestIdx = N;
#pragma unroll
    for (int r = 0; r < 8; ++r) {
        const int idx = (tid << 3) + r;
        run1 += (double)v[r];
        run2 += (double)v[r] * (double)v[r];
        if (idx < N - 1) {
            const double kf  = (double)(idx + 1);
            const double Sw1 = run2 - run1 * run1 / kf;
            const double rem = total1 - run1;
            const double Sw2 = total2 - run2 - rem * rem / (nf - kf);
            const double obj = (Sw1 + Sw2) / Sb;
            if (obj < bestObj) { bestObj = obj; bestIdx = idx; bestCs = run1; }
        }
    }

    // ---- wave argmin reduce (min obj, first index on ties) ----
#pragma unroll
    for (int off = 32; off > 0; off >>= 1) {
        const double oObj = __shfl_down(bestObj, off, 64);
        const int    oIdx = __shfl_down(bestIdx, off, 64);
        const double oCs  = __shfl_down(bestCs, off, 64);
        if (oObj < bestObj || (oObj == bestObj && oIdx < bestIdx)) {
            bestObj = oObj; bestIdx = oIdx; bestCs = oCs;
        }
    }
    if (lane == 0) { redObj[wv] = bestObj; redIdx[wv] = bestIdx; redCs[wv] = bestCs; }
    __syncthreads();

    if (tid == 0) {
        double bObj = redObj[0], bCs = redCs[0];
        int bIdx = redIdx[0];
        for (int w = 1; w < 16; ++w) {
            if (redObj[w] < bObj || (redObj[w] == bObj && redIdx[w] < bIdx)) {
                bObj = redObj[w]; bIdx = redIdx[w]; bCs = redCs[w];
            }
        }
        const double T = (double)(bIdx + 1);
        out[0] = (float)(bCs / T + LAMB * bObj);
    }
}

// ---------------------------------------------------------------------------
extern "C" void kernel_launch(void* const* d_in, const int* in_sizes, int n_in,
                              void* d_out, int out_size, void* d_ws, size_t ws_size,
                              hipStream_t stream) {
    const float* inp = (const float*)d_in[0];
    const float* tgt = (const float*)d_in[1];
    float* errbuf = (float*)d_ws;   // 8192 f32 = 32 KB scratch

    rowerr_kernel<<<NROWS, 256, 0, stream>>>(inp, tgt, errbuf);
    drae_kernel<<<1, 1024, 0, stream>>>(errbuf, (float*)d_out);
}